// Round 2
// baseline (385.717 us; speedup 1.0000x reference)
//
#include <hip/hip_runtime.h>
#include <cstdint>
#include <cstddef>

typedef unsigned short u16;
typedef unsigned int   u32;
typedef unsigned long long u64;
typedef __attribute__((ext_vector_type(8))) short short8;   // 8 bf16 = 4 VGPR
typedef __attribute__((ext_vector_type(4))) float f32x4;

#define M_ROWS 16384
#define N_COLS 256
#define IN_F   1024
#define K_SPL  8192   // 1024 features * 8 basis
#define K_TOT  9216   // + 1024 base (silu) features
// BK=32 chunks: 288 total (256 spline chunks of 4 features, 32 base chunks of 32 feats)
#define NCHUNK 288
#define SPLITK 4
#define CPB    (NCHUNK / SPLITK)   // 72 chunks per block

// ---------- helpers ----------
__device__ __forceinline__ u32 f2bf1(float f) {          // f32 -> bf16 bits, RNE
  u32 u = __float_as_uint(f);
  u += 0x7fffu + ((u >> 16) & 1u);
  return u >> 16;
}
__device__ __forceinline__ u32 pk2(float a, float b) {
  return f2bf1(a) | (f2bf1(b) << 16);
}
__device__ __forceinline__ float silu(float v) {
  return v * __builtin_amdgcn_rcpf(1.f + __expf(-v));
}

// 8 bf16 cubic B-spline basis values for one x, packed as uint4 (16B).
// u = 2.5x + 5.5; basis_j(x) = N3(u - j); 4 nonzero wts scattered via funnel shift.
__device__ __forceinline__ uint4 basis8(float xv) {
  float u = fmaf(xv, 2.5f, 5.5f);
  int i0 = (int)u;
  float fr = u - (float)i0;
  float fr2 = fr * fr, fr3 = fr2 * fr;
  float om  = 1.f - fr;
  float om3 = om * om * om;
  float w0 = om3 * (1.f / 6.f);
  float w3 = fr3 * (1.f / 6.f);
  float w1 = fmaf(fr3, 0.5f, fmaf(fr2, -1.f, 2.f / 3.f));
  float w2 = fmaf(fr + fr2 - fr3, 0.5f, 1.f / 6.f);
  u64 W = (u64)pk2(w0, w1) | ((u64)pk2(w2, w3) << 32);
  if (!(u >= 0.f && u < 11.f)) W = 0ull;
  int s = (i0 - 3) * 16;
  u64 lo, hi;
  if (s >= 64)      { int r = s - 64; lo = 0ull; hi = (r < 64) ? (W << r) : 0ull; }
  else if (s > 0)   { lo = W << s;    hi = W >> (64 - s); }
  else if (s == 0)  { lo = W;         hi = 0ull; }
  else              { int r = -s;     lo = (r < 64) ? (W >> r) : 0ull; hi = 0ull; }
  uint4 o;
  o.x = (u32)lo; o.y = (u32)(lo >> 32); o.z = (u32)hi; o.w = (u32)(hi >> 32);
  return o;
}

// ---------- kernel 1: pack [spline_weight | base_weight] -> bf16, (256 x 9216) row-major ----------
__global__ void pack_weights(const float* __restrict__ bw, const float* __restrict__ sw,
                             u16* __restrict__ Bp) {
  int o  = blockIdx.y;
  int k4 = (blockIdx.x * blockDim.x + threadIdx.x) * 4;
  const float* src = (k4 < K_SPL) ? (sw + (size_t)o * K_SPL + k4)
                                  : (bw + (size_t)o * IN_F + (k4 - K_SPL));
  float a = src[0], b = src[1], c = src[2], d = src[3];
  uint2 v; v.x = pk2(a, b); v.y = pk2(c, d);
  *(uint2*)(Bp + (size_t)o * K_TOT + k4) = v;
}

// ---------- kernel 2: fused KAN GEMM ----------
// R2 theory: R1 was latency-bound (MfmaUtil 25 + VALUBusy 40, ~35% no-issue,
// occupancy 38% = only 4 waves/SIMD). Fix: BK 64->32 shrinks LDS to 40 KB
// (As dbuf 8K + Bs dbuf 32K) -> 4 blocks/CU = 32 waves/CU (thread-slot max).
// Grid 1024 via split-K=4 (CPB=72, same per-block barrier count as R1).
// VGPR must stay <=64 for 8 waves/SIMD: __launch_bounds__(512,8).
// XCD remap: all 4 split-K partners of one output tile on the SAME XCD so the
// atomic out-lines stay L2-local (bijective: 1024 = 8 XCD * 128).
// Swizzle for 64B row stride: chunk' = chunk ^ ((row>>1)&3) -> 2-way (free).
// Structure unchanged from R1: dbuf, 1 barrier/chunk, prefetch before MFMA.
__global__ __launch_bounds__(512, 8)
void kan_gemm(const float* __restrict__ x, const u16* __restrict__ Bp,
              float* __restrict__ out) {
  __shared__ __align__(16) u16 Bs[2 * 256 * 32];   // 32 KB (2 bufs)
  __shared__ __align__(16) u16 As[2 * 64 * 32];    //  8 KB (2 bufs)

  const int tid  = threadIdx.x;
  const int lane = tid & 63;
  const int w    = tid >> 6;          // 0..7
  const int wm   = w & 1;             // m-half (32 rows)
  const int wn   = w >> 1;            // n-quarter (64 cols)

  const int p    = blockIdx.x;        // 1024
  const int kid  = (p >> 3) & 3;      // split-K id: partners share XCD (p%8)
  const int mb   = (p & 7) + ((p >> 5) << 3);   // 0..255
  const int row0 = mb * 64;
  const int cs   = kid * CPB, c1 = cs + CPB;

  f32x4 acc[2][4];
#pragma unroll
  for (int i = 0; i < 2; ++i)
#pragma unroll
    for (int j = 0; j < 4; ++j)
      acc[i][j] = (f32x4){0.f, 0.f, 0.f, 0.f};

  // builder mapping: threads 0..255 build A (64 rows x 4 feature-chunks)
  const int  br      = tid >> 2;      // row 0..63
  const int  bq      = tid & 3;       // feature-chunk 0..3
  const bool builder = tid < 256;
  const int  a_wr    = br * 32 + ((bq ^ ((br >> 1) & 3)) * 8);  // swizzled u16 idx

  // fragment read offsets (u16 index within one buffer), swizzled for 64B rows
  const int lm = lane & 15;
  const int kg = lane >> 4;           // k-group 0..3 (k = kg*8..+7 within BK=32)
  int a_off[2], b_off[4];
#pragma unroll
  for (int i = 0; i < 2; ++i) {
    int ra = wm * 32 + i * 16 + lm;
    a_off[i] = ra * 32 + ((kg ^ ((ra >> 1) & 3)) * 8);
  }
#pragma unroll
  for (int j = 0; j < 4; ++j) {
    int rb = wn * 64 + j * 16 + lm;
    b_off[j] = rb * 32 + ((kg ^ ((rb >> 1) & 3)) * 8);
  }

  // B staging: 512 thr x 2 iters x 16B = 16 KB chunk; linear LDS dest,
  // inverse-swizzled global source (both-sides-or-neither rule).
  u32 stage_goff[2];
  int stage_loff[2];
#pragma unroll
  for (int it = 0; it < 2; ++it) {
    int s  = tid + it * 512;
    int r_ = s >> 2, cc = s & 3;
    stage_goff[it] = (u32)r_ * K_TOT + ((cc ^ ((r_ >> 1) & 3)) * 8);
    stage_loff[it] = s * 8;
  }

  float px;            // spline prefetch (1 feature, builders only)
  float4 pb0, pb1;     // base prefetch (8 features, builders only)

  auto LOADX = [&](int c) {
    if (!builder) return;
    if (c < 256) {
      px = x[(size_t)(row0 + br) * IN_F + c * 4 + bq];
    } else {
      const float* xp = x + (size_t)(row0 + br) * IN_F + (c - 256) * 32 + bq * 8;
      pb0 = *(const float4*)xp;
      pb1 = *(const float4*)(xp + 4);
    }
  };

  auto BUILD = [&](int c, int buf) {
    if (!builder) return;
    uint4 q;
    if (c < 256) {
      q = basis8(px);
    } else {
      q.x = pk2(silu(pb0.x), silu(pb0.y));
      q.y = pk2(silu(pb0.z), silu(pb0.w));
      q.z = pk2(silu(pb1.x), silu(pb1.y));
      q.w = pk2(silu(pb1.z), silu(pb1.w));
    }
    *(uint4*)(As + buf * (64 * 32) + a_wr) = q;
  };

  auto STAGEB = [&](int c, int buf) {
    u16* base = Bs + buf * (256 * 32);
#pragma unroll
    for (int it = 0; it < 2; ++it) {
      const u16* gp = Bp + stage_goff[it] + c * 32;
      __builtin_amdgcn_global_load_lds((const __attribute__((address_space(1))) void*)gp,
                                       (__attribute__((address_space(3))) void*)(base + stage_loff[it]),
                                       16, 0, 0);
    }
  };

  auto MFMA_PHASE = [&](int buf) {
    const u16* Ab = As + buf * (64 * 32);
    const u16* Bb = Bs + buf * (256 * 32);
    short8 af[2], bf[4];
#pragma unroll
    for (int i = 0; i < 2; ++i) af[i] = *(const short8*)(Ab + a_off[i]);
#pragma unroll
    for (int j = 0; j < 4; ++j) bf[j] = *(const short8*)(Bb + b_off[j]);
#pragma unroll
    for (int i = 0; i < 2; ++i)
#pragma unroll
      for (int j = 0; j < 4; ++j)
        acc[i][j] = __builtin_amdgcn_mfma_f32_16x16x32_bf16(af[i], bf[j], acc[i][j], 0, 0, 0);
  };

  // ---- prologue: chunk cs -> buf 0 ----
  LOADX(cs);
  STAGEB(cs, 0);
  BUILD(cs, 0);
  if (cs + 1 < c1) LOADX(cs + 1);
  __syncthreads();   // buf0 ready

  // ---- main loop: 1 barrier per chunk, x2 unrolled for static buffer idx ----
  for (int c = cs; c < c1; c += 2) {
    // chunk c on buf0; prefetch chunk c+1 -> buf1
    if (c + 1 < c1) { STAGEB(c + 1, 1); BUILD(c + 1, 1); }
    if (c + 2 < c1) LOADX(c + 2);
    MFMA_PHASE(0);
    __syncthreads();

    // chunk c+1 on buf1; prefetch chunk c+2 -> buf0
    if (c + 1 < c1) {
      if (c + 2 < c1) { STAGEB(c + 2, 0); BUILD(c + 2, 0); }
      if (c + 3 < c1) LOADX(c + 3);
      MFMA_PHASE(1);
      __syncthreads();
    }
  }

  // ---- epilogue: C/D layout col=lane&15, row=(lane>>4)*4+reg; split-K -> atomic add ----
  const int lc = lane & 15;
  const int lr = (lane >> 4) * 4;
#pragma unroll
  for (int i = 0; i < 2; ++i) {
#pragma unroll
    for (int j = 0; j < 4; ++j) {
      int gr = row0 + wm * 32 + i * 16 + lr;
      int gc = wn * 64 + j * 16 + lc;
      float* po = out + (size_t)gr * N_COLS + gc;
#pragma unroll
      for (int r = 0; r < 4; ++r)
        unsafeAtomicAdd(po + (size_t)r * N_COLS, acc[i][j][r]);
    }
  }
}

extern "C" void kernel_launch(void* const* d_in, const int* in_sizes, int n_in,
                              void* d_out, int out_size, void* d_ws, size_t ws_size,
                              hipStream_t stream) {
  const float* x  = (const float*)d_in[0];   // 16384 x 1024
  const float* bw = (const float*)d_in[1];   // 256 x 1024
  const float* sw = (const float*)d_in[2];   // 256 x 8192
  float* out = (float*)d_out;                // 16384 x 256 f32
  u16* Bp = (u16*)d_ws;                      // 256 x 9216 bf16 = 4.5 MB

  hipMemsetAsync(d_out, 0, (size_t)M_ROWS * N_COLS * sizeof(float), stream);

  dim3 pgrid(K_TOT / 4 / 256, N_COLS);       // (9, 256)
  pack_weights<<<pgrid, 256, 0, stream>>>(bw, sw, Bp);

  kan_gemm<<<1024, 512, 0, stream>>>(x, Bp, out);
}

// Round 4
// 204.893 us; speedup vs baseline: 1.8825x; 1.8825x over previous
//
#include <hip/hip_runtime.h>
#include <cstdint>
#include <cstddef>

typedef unsigned short u16;
typedef unsigned int   u32;
typedef unsigned long long u64;
typedef __attribute__((ext_vector_type(8))) short short8;   // 8 bf16 = 4 VGPR
typedef __attribute__((ext_vector_type(4))) float f32x4;

#define M_ROWS 16384
#define N_COLS 256
#define IN_F   1024
#define K_SPL  8192   // 1024 features * 8 basis
#define K_TOT  9216   // + 1024 base (silu) features
// BK=64 chunks: 144 total (128 spline chunks of 8 features, 16 base chunks of 64 feats)
#define NCHUNK 144
#define SPLITK 2
#define CPB    (NCHUNK / SPLITK)   // 72 chunks per block

// ---------- helpers ----------
__device__ __forceinline__ u32 f2bf1(float f) {          // f32 -> bf16 bits, RNE
  u32 u = __float_as_uint(f);
  u += 0x7fffu + ((u >> 16) & 1u);
  return u >> 16;
}
__device__ __forceinline__ u32 pk2(float a, float b) {
  return f2bf1(a) | (f2bf1(b) << 16);
}
__device__ __forceinline__ float silu(float v) {
  return v * __builtin_amdgcn_rcpf(1.f + __expf(-v));
}

// 8 bf16 cubic B-spline basis values for one x, packed as uint4 (16B).
// u = 2.5x + 5.5; basis_j(x) = N3(u - j); 4 nonzero wts scattered via funnel shift.
__device__ __forceinline__ uint4 basis8(float xv) {
  float u = fmaf(xv, 2.5f, 5.5f);
  int i0 = (int)u;
  float fr = u - (float)i0;
  float fr2 = fr * fr, fr3 = fr2 * fr;
  float om  = 1.f - fr;
  float om3 = om * om * om;
  float w0 = om3 * (1.f / 6.f);
  float w3 = fr3 * (1.f / 6.f);
  float w1 = fmaf(fr3, 0.5f, fmaf(fr2, -1.f, 2.f / 3.f));
  float w2 = fmaf(fr + fr2 - fr3, 0.5f, 1.f / 6.f);
  u64 W = (u64)pk2(w0, w1) | ((u64)pk2(w2, w3) << 32);
  if (!(u >= 0.f && u < 11.f)) W = 0ull;
  int s = (i0 - 3) * 16;
  u64 lo, hi;
  if (s >= 64)      { int r = s - 64; lo = 0ull; hi = (r < 64) ? (W << r) : 0ull; }
  else if (s > 0)   { lo = W << s;    hi = W >> (64 - s); }
  else if (s == 0)  { lo = W;         hi = 0ull; }
  else              { int r = -s;     lo = (r < 64) ? (W >> r) : 0ull; hi = 0ull; }
  uint4 o;
  o.x = (u32)lo; o.y = (u32)(lo >> 32); o.z = (u32)hi; o.w = (u32)(hi >> 32);
  return o;
}

// ---------- kernel 1: pack [spline_weight | base_weight] -> bf16, (256 x 9216) row-major ----------
__global__ void pack_weights(const float* __restrict__ bw, const float* __restrict__ sw,
                             u16* __restrict__ Bp) {
  int o  = blockIdx.y;
  int k4 = (blockIdx.x * blockDim.x + threadIdx.x) * 4;
  const float* src = (k4 < K_SPL) ? (sw + (size_t)o * K_SPL + k4)
                                  : (bw + (size_t)o * IN_F + (k4 - K_SPL));
  float a = src[0], b = src[1], c = src[2], d = src[3];
  uint2 v; v.x = pk2(a, b); v.y = pk2(c, d);
  *(uint2*)(Bp + (size_t)o * K_TOT + k4) = v;
}

// ---------- kernel 2: fused KAN GEMM ----------
// R4 = R3 resubmit (container infra failure, no kernel verdict).
// Theory: R2 proved occupancy rise via split-K=4/BK=32 multiplies HBM traffic
// (atomic RMW evictions + L2 thrash) -> memory-bound disaster. Revert to the
// R0/R1-proven traffic shape (BM=64 BN=256 BK=64, split-K=2 ADJACENT partners,
// FETCH ~76MB WRITE ~33MB) and instead raise occupancy with 1024-thread
// blocks: 16 waves (4m x 4n, wave tile 16x64, acc 1x4), LDS 80KB -> exactly
// 2 blocks/CU = 2048 threads = 32 waves/CU (8/SIMD, double R1). VGPR<=64
// enforced by __launch_bounds__(1024,8); acc is only 16 regs now.
// A-build rotated between thread-halves by chunk parity (static in the x2
// unrolled loop) so build-VALU spreads over all 16 waves.
// Structure otherwise identical to R1: dbuf, 1 barrier/chunk, prefetch
// (STAGEB+BUILD of next chunk) issued before current MFMA phase.
// LDS 16B-chunk swizzle: chunk u of row r at slot r*8 + (u ^ (r&7)).
__global__ __launch_bounds__(1024, 8)
void kan_gemm(const float* __restrict__ x, const u16* __restrict__ Bp,
              float* __restrict__ out) {
  __shared__ __align__(16) u16 Bs[2 * 256 * 64];   // 64 KB (2 bufs)
  __shared__ __align__(16) u16 As[2 * 64 * 64];    // 16 KB (2 bufs)

  const int tid  = threadIdx.x;
  const int lane = tid & 63;
  const int w    = tid >> 6;          // 0..15
  const int wm   = w & 3;             // m-quarter (16 rows)
  const int wn   = w >> 2;            // n-quarter (64 cols)

  const int bid  = blockIdx.x;        // 512
  const int kid  = bid & 1;           // adjacent split-K partners (R0-proven)
  const int mb   = bid >> 1;          // 0..255
  const int row0 = mb * 64;
  const int cs   = kid * CPB, c1 = cs + CPB;   // cs even (CPB=72)

  f32x4 acc[4];
#pragma unroll
  for (int j = 0; j < 4; ++j) acc[j] = (f32x4){0.f, 0.f, 0.f, 0.f};

  // builder mapping: 512 builds/chunk (64 rows x 8 feat-chunks); thread-half
  // bgrp builds chunks with (c&1)==bgrp.
  const int sr   = (tid >> 3) & 63;   // row 0..63
  const int sq   = tid & 7;           // 16B feature-chunk 0..7
  const int bgrp = tid >> 9;          // 0 or 1

  // fragment read offsets (u16 index within one buffer), swizzled.
  // h=1 offset = h=0 offset ^ 32 (since (4|kg)^(r&7) == (kg^(r&7))^4).
  const int lm = lane & 15;
  const int kg = lane >> 4;
  const int ra = wm * 16 + lm;
  const int a_base = ra * 64 + ((kg ^ (ra & 7)) * 8);
  int b_base[4];
#pragma unroll
  for (int j = 0; j < 4; ++j) {
    int rb = wn * 64 + j * 16 + lm;
    b_base[j] = rb * 64 + ((kg ^ (rb & 7)) * 8);
  }

  // B staging: 1024 thr x 2 iters x 16B = 32 KB chunk; linear LDS dest,
  // inverse-swizzled global source (both-sides-or-neither rule).
  u32 stage_goff[2];
  int stage_loff[2];
#pragma unroll
  for (int it = 0; it < 2; ++it) {
    int s  = tid + it * 1024;
    int r_ = s >> 3, cc = (s & 7) ^ (r_ & 7);
    stage_goff[it] = (u32)r_ * K_TOT + cc * 8;
    stage_loff[it] = s * 8;
  }

  float px;            // spline prefetch (1 feature, active bgrp only)
  float4 pb0, pb1;     // base prefetch (8 features, active bgrp only)

  auto LOADX = [&](int c) {
    if ((c & 1) != bgrp) return;
    if (c < 128) {
      px = x[(size_t)(row0 + sr) * IN_F + c * 8 + sq];
    } else {
      const float* xp = x + (size_t)(row0 + sr) * IN_F + (c - 128) * 64 + sq * 8;
      pb0 = *(const float4*)xp;
      pb1 = *(const float4*)(xp + 4);
    }
  };

  auto BUILD = [&](int c, int buf) {
    if ((c & 1) != bgrp) return;
    uint4 q;
    if (c < 128) {
      q = basis8(px);
    } else {
      q.x = pk2(silu(pb0.x), silu(pb0.y));
      q.y = pk2(silu(pb0.z), silu(pb0.w));
      q.z = pk2(silu(pb1.x), silu(pb1.y));
      q.w = pk2(silu(pb1.z), silu(pb1.w));
    }
    *(uint4*)(As + buf * (64 * 64) + sr * 64 + ((sq ^ (sr & 7)) * 8)) = q;
  };

  auto STAGEB = [&](int c, int buf) {
    u16* base = Bs + buf * (256 * 64);
#pragma unroll
    for (int it = 0; it < 2; ++it) {
      const u16* gp = Bp + stage_goff[it] + c * 64;
      __builtin_amdgcn_global_load_lds((const __attribute__((address_space(1))) void*)gp,
                                       (__attribute__((address_space(3))) void*)(base + stage_loff[it]),
                                       16, 0, 0);
    }
  };

  auto MFMA_PHASE = [&](int buf) {
    const u16* Ab = As + buf * (64 * 64);
    const u16* Bb = Bs + buf * (256 * 64);
#pragma unroll
    for (int h = 0; h < 2; ++h) {
      const int hx = h * 32;          // offset XOR for k-half
      short8 af = *(const short8*)(Ab + (a_base ^ hx));
      short8 bf[4];
#pragma unroll
      for (int j = 0; j < 4; ++j) bf[j] = *(const short8*)(Bb + (b_base[j] ^ hx));
#pragma unroll
      for (int j = 0; j < 4; ++j)
        acc[j] = __builtin_amdgcn_mfma_f32_16x16x32_bf16(af, bf[j], acc[j], 0, 0, 0);
    }
  };

  // ---- prologue: chunk cs -> buf 0 ----
  LOADX(cs);
  STAGEB(cs, 0);
  BUILD(cs, 0);
  if (cs + 1 < c1) LOADX(cs + 1);
  __syncthreads();   // buf0 ready

  // ---- main loop: 1 barrier per chunk, x2 unrolled for static buffer idx ----
  for (int c = cs; c < c1; c += 2) {
    // chunk c on buf0; prefetch chunk c+1 -> buf1
    if (c + 1 < c1) { STAGEB(c + 1, 1); BUILD(c + 1, 1); }
    if (c + 2 < c1) LOADX(c + 2);
    MFMA_PHASE(0);
    __syncthreads();

    // chunk c+1 on buf1; prefetch chunk c+2 -> buf0
    if (c + 1 < c1) {
      if (c + 2 < c1) { STAGEB(c + 2, 0); BUILD(c + 2, 0); }
      if (c + 3 < c1) LOADX(c + 3);
      MFMA_PHASE(1);
      __syncthreads();
    }
  }

  // ---- epilogue: C/D layout col=lane&15, row=(lane>>4)*4+reg; split-K=2 -> atomic add ----
  const int lc = lane & 15;
  const int lr = (lane >> 4) * 4;
#pragma unroll
  for (int j = 0; j < 4; ++j) {
    int gr = row0 + wm * 16 + lr;
    int gc = wn * 64 + j * 16 + lc;
    float* po = out + (size_t)gr * N_COLS + gc;
#pragma unroll
    for (int r = 0; r < 4; ++r)
      unsafeAtomicAdd(po + (size_t)r * N_COLS, acc[j][r]);
  }
}

extern "C" void kernel_launch(void* const* d_in, const int* in_sizes, int n_in,
                              void* d_out, int out_size, void* d_ws, size_t ws_size,
                              hipStream_t stream) {
  const float* x  = (const float*)d_in[0];   // 16384 x 1024
  const float* bw = (const float*)d_in[1];   // 256 x 1024
  const float* sw = (const float*)d_in[2];   // 256 x 8192
  float* out = (float*)d_out;                // 16384 x 256 f32
  u16* Bp = (u16*)d_ws;                      // 256 x 9216 bf16 = 4.5 MB

  hipMemsetAsync(d_out, 0, (size_t)M_ROWS * N_COLS * sizeof(float), stream);

  dim3 pgrid(K_TOT / 4 / 256, N_COLS);       // (9, 256)
  pack_weights<<<pgrid, 256, 0, stream>>>(bw, sw, Bp);

  kan_gemm<<<512, 1024, 0, stream>>>(x, Bp, out);
}